// Round 1
// baseline (1079.886 us; speedup 1.0000x reference)
//
#include <hip/hip_runtime.h>
#include <hip/hip_bf16.h>

// ChildSumTreeLSTM on MI355X — round 0: fp32 level-batched implementation.
//
// Tree: reversed complete 4-ary heap, node ids contiguous per level,
// children ids < parent id. Level boundaries (ascending = leaves first):
//   [0,2731) [2731,3755) [3755,4011) [4011,4075) [4075,4091) [4091,4095) [4095,4096)
//
// Pipeline:
//   XW = inputs @ Wx + bx            (one 4096x512x2048 GEMM, hoisted)
//   per level: gather child h -> Hch[4L,512], Hsum[L,512]
//              IOU  = Hsum @ Ws + bs (L x 512 x 1536)
//              Fpre = Hch  @ Wf + bf (4L x 512 x 512)
//              elementwise gates -> cbuf[n], hbuf[n]
//   out = hbuf[4095]

#define NN    4096
#define KCH   4
#define IND   512
#define MEM   512

static __device__ __forceinline__ float sigmoidf_(float x) {
    return 1.0f / (1.0f + __expf(-x));
}

// ---------------- zero sentinel rows (id NN) of cbuf/hbuf -------------------
__global__ void zero_sentinel(float* __restrict__ cbuf, float* __restrict__ hbuf) {
    int d = threadIdx.x;           // 512 threads
    cbuf[(size_t)NN * MEM + d] = 0.0f;
    hbuf[(size_t)NN * MEM + d] = 0.0f;
}

// ---------------- fp32 tiled GEMM: C[M,Nn] = A[M,Kd] @ B[Kd,Nn] + bias ------
// BM=BN=128, BK=8, 256 threads, 8x8 per thread. A staged transposed in LDS.
__global__ __launch_bounds__(256) void gemm128(const float* __restrict__ A,
                                               const float* __restrict__ B,
                                               const float* __restrict__ bias,
                                               float* __restrict__ C,
                                               int M, int Nn, int Kd) {
    __shared__ float As[8][128];   // As[k][m]
    __shared__ float Bs[8][128];   // Bs[k][n]

    const int bn = blockIdx.x * 128;
    const int bm = blockIdx.y * 128;
    const int tid = threadIdx.x;
    const int tr = tid >> 4;       // 0..15
    const int tc = tid & 15;       // 0..15

    // staging indices
    const int lar = tid >> 1;          // 0..127 (A tile row)
    const int lac = (tid & 1) * 4;     // 0 or 4 (A tile col group)
    const int lbr = tid >> 5;          // 0..7   (B tile row)
    const int lbc = (tid & 31) * 4;    // 0..124 (B tile col group)

    float acc[8][8];
#pragma unroll
    for (int x = 0; x < 8; ++x)
#pragma unroll
        for (int y = 0; y < 8; ++y) acc[x][y] = 0.0f;

    for (int k0 = 0; k0 < Kd; k0 += 8) {
        float4 av;
        if (bm + lar < M)
            av = *(const float4*)(A + (size_t)(bm + lar) * Kd + k0 + lac);
        else
            av = make_float4(0.f, 0.f, 0.f, 0.f);
        float4 bv = *(const float4*)(B + (size_t)(k0 + lbr) * Nn + bn + lbc);

        __syncthreads();   // previous iter's reads done before overwrite
        As[lac + 0][lar] = av.x;
        As[lac + 1][lar] = av.y;
        As[lac + 2][lar] = av.z;
        As[lac + 3][lar] = av.w;
        *(float4*)(&Bs[lbr][lbc]) = bv;
        __syncthreads();

#pragma unroll
        for (int kk = 0; kk < 8; ++kk) {
            float a[8], b[8];
            *(float4*)(a)     = *(const float4*)(&As[kk][tr * 8]);
            *(float4*)(a + 4) = *(const float4*)(&As[kk][tr * 8 + 4]);
            *(float4*)(b)     = *(const float4*)(&Bs[kk][tc * 8]);
            *(float4*)(b + 4) = *(const float4*)(&Bs[kk][tc * 8 + 4]);
#pragma unroll
            for (int x = 0; x < 8; ++x)
#pragma unroll
                for (int y = 0; y < 8; ++y)
                    acc[x][y] = fmaf(a[x], b[y], acc[x][y]);
        }
    }

#pragma unroll
    for (int x = 0; x < 8; ++x) {
        int r = bm + tr * 8 + x;
        if (r < M) {
            float* crow = C + (size_t)r * Nn + bn + tc * 8;
            const float* brow = bias + bn + tc * 8;
#pragma unroll
            for (int y = 0; y < 8; ++y) crow[y] = acc[x][y] + brow[y];
        }
    }
}

// ---------------- gather children h -> Hch[4L,512], Hsum[L,512] -------------
__global__ void gather_children(const int* __restrict__ children,
                                const float* __restrict__ hbuf,
                                float* __restrict__ Hch,
                                float* __restrict__ Hsum,
                                int lo) {
    const int i = blockIdx.x;         // node index within level
    const int n = lo + i;
    const int d = threadIdx.x;        // 512 threads
    const int* kids = children + (size_t)n * KCH;
    float s = 0.0f;
#pragma unroll
    for (int k = 0; k < KCH; ++k) {
        float h = hbuf[(size_t)kids[k] * MEM + d];
        Hch[((size_t)i * KCH + k) * MEM + d] = h;
        s += h;
    }
    Hsum[(size_t)i * MEM + d] = s;
}

// ---------------- elementwise node update -----------------------------------
__global__ void node_update(const float* __restrict__ XW,
                            const float* __restrict__ IOU,
                            const float* __restrict__ Fpre,
                            const int* __restrict__ children,
                            const float* __restrict__ bs,
                            float* __restrict__ cbuf,
                            float* __restrict__ hbuf,
                            int lo, int leaf) {
    const int i = blockIdx.x;
    const int n = lo + i;
    const int d = threadIdx.x;        // 512 threads

    const float* xwr = XW + (size_t)n * (4 * MEM);
    const float ix = xwr[d];
    const float fx = xwr[MEM + d];
    const float ox = xwr[2 * MEM + d];
    const float ux = xwr[3 * MEM + d];

    float i_s, o_s, u_s;
    if (leaf) {
        i_s = bs[d];
        o_s = bs[MEM + d];
        u_s = bs[2 * MEM + d];
    } else {
        const float* r = IOU + (size_t)i * (3 * MEM);
        i_s = r[d];
        o_s = r[MEM + d];
        u_s = r[2 * MEM + d];
    }

    const float ig = sigmoidf_(ix + i_s);
    const float og = sigmoidf_(ox + o_s);
    const float ug = tanhf(ux + u_s);
    float c = ig * ug;

    if (!leaf) {
        const int* kids = children + (size_t)n * KCH;
#pragma unroll
        for (int k = 0; k < KCH; ++k) {
            const float f = sigmoidf_(Fpre[((size_t)i * KCH + k) * MEM + d] + fx);
            c += f * cbuf[(size_t)kids[k] * MEM + d];
        }
    }

    cbuf[(size_t)n * MEM + d] = c;
    hbuf[(size_t)n * MEM + d] = og * tanhf(c);
}

// ---------------- copy root h to output --------------------------------------
__global__ void copy_out(const float* __restrict__ hbuf, float* __restrict__ out) {
    int d = threadIdx.x;              // 512 threads
    out[d] = hbuf[(size_t)(NN - 1) * MEM + d];
}

extern "C" void kernel_launch(void* const* d_in, const int* in_sizes, int n_in,
                              void* d_out, int out_size, void* d_ws, size_t ws_size,
                              hipStream_t stream) {
    const float* inputs   = (const float*)d_in[0];
    const float* Wx       = (const float*)d_in[1];
    const float* bx       = (const float*)d_in[2];
    const float* Ws       = (const float*)d_in[3];
    const float* bs       = (const float*)d_in[4];
    const float* Wf       = (const float*)d_in[5];
    const float* bf       = (const float*)d_in[6];
    const int*   children = (const int*)d_in[7];
    float* out = (float*)d_out;

    float* ws = (float*)d_ws;
    float* XW   = ws;                              // 4096*2048
    float* cbuf = XW   + (size_t)NN * 4 * MEM;     // 4097*512
    float* hbuf = cbuf + (size_t)(NN + 1) * MEM;   // 4097*512
    float* Hsum = hbuf + (size_t)(NN + 1) * MEM;   // 1024*512
    float* Hch  = Hsum + (size_t)1024 * MEM;       // 4096*512
    float* IOU  = Hch  + (size_t)4096 * MEM;       // 1024*1536
    float* Fpre = IOU  + (size_t)1024 * 3 * MEM;   // 4096*512

    // level boundaries (node ids), leaves first
    static const int lvl_lo[7] = {0, 2731, 3755, 4011, 4075, 4091, 4095};
    static const int lvl_hi[7] = {2731, 3755, 4011, 4075, 4091, 4095, 4096};

    zero_sentinel<<<1, 512, 0, stream>>>(cbuf, hbuf);

    // XW = inputs @ Wx + bx   [4096,512]x[512,2048]
    gemm128<<<dim3(2048 / 128, 4096 / 128), 256, 0, stream>>>(
        inputs, Wx, bx, XW, NN, 4 * MEM, IND);

    // leaves: no children contributions
    node_update<<<lvl_hi[0] - lvl_lo[0], 512, 0, stream>>>(
        XW, nullptr, nullptr, children, bs, cbuf, hbuf, lvl_lo[0], 1);

    for (int l = 1; l < 7; ++l) {
        const int lo = lvl_lo[l];
        const int L  = lvl_hi[l] - lvl_lo[l];

        gather_children<<<L, 512, 0, stream>>>(children, hbuf, Hch, Hsum, lo);

        // IOU = Hsum @ Ws + bs   [L,512]x[512,1536]
        gemm128<<<dim3((3 * MEM) / 128, (L + 127) / 128), 256, 0, stream>>>(
            Hsum, Ws, bs, IOU, L, 3 * MEM, MEM);

        // Fpre = Hch @ Wf + bf   [4L,512]x[512,512]
        gemm128<<<dim3(MEM / 128, (4 * L + 127) / 128), 256, 0, stream>>>(
            Hch, Wf, bf, Fpre, 4 * L, MEM, MEM);

        node_update<<<L, 512, 0, stream>>>(
            XW, IOU, Fpre, children, bs, cbuf, hbuf, lo, 0);
    }

    copy_out<<<1, 512, 0, stream>>>(hbuf, out);
}

// Round 2
// 335.632 us; speedup vs baseline: 3.2175x; 3.2175x over previous
//
#include <hip/hip_runtime.h>
#include <hip/hip_bf16.h>

// ChildSumTreeLSTM on MI355X — round 2: bf16 MFMA GEMMs, fused gather, fp32 state.
//
// Tree: reversed complete 4-ary heap, N=4096. Leaves = ids [0,3072).
// Internal levels (children of level l are exactly level l-1):
//   [3072,3755) L=683 | [3755,4011) 256 | [4011,4075) 64 | [4075,4091) 16
//   [4091,4095) 4 | [4095,4096) 1
//
// Pipeline:
//   prep: inputs->bf16, weights->bf16 transposed (k-contiguous), zero sentinels
//   XW = inputs @ Wx + bx          (bf16 MFMA [4096,512]x[512,2048], fp32 out)
//   leaves: elementwise from XW + bs
//   per level: IOU-GEMM (A = on-the-fly child-h sum), F-GEMM (A = child h rows),
//              elementwise update (fp32 c, bf16 h)

#define NN   4096
#define MEM  512
#define KD   512

typedef __attribute__((ext_vector_type(8))) short bf16x8;
typedef __attribute__((ext_vector_type(4))) float f32x4;

static __device__ __forceinline__ unsigned short f2bf(float f) {
    union { float f; unsigned int u; } v; v.f = f;
    unsigned int r = v.u + 0x7FFF + ((v.u >> 16) & 1);   // RTN-even
    return (unsigned short)(r >> 16);
}
static __device__ __forceinline__ float bf2f(unsigned short s) {
    union { unsigned int u; float f; } v; v.u = ((unsigned int)s) << 16;
    return v.f;
}
static __device__ __forceinline__ float sigmoidf_(float x) {
    return 1.0f / (1.0f + __expf(-x));
}
static __device__ __forceinline__ bf16x8 zero8() {
    bf16x8 z = {0, 0, 0, 0, 0, 0, 0, 0};
    return z;
}

// ---------------- prep: inputs -> bf16 row-major, zero sentinel rows ---------
__global__ void prep_x(const float* __restrict__ in, unsigned short* __restrict__ Xb,
                       float* __restrict__ cbuf, unsigned short* __restrict__ hb) {
    int idx = blockIdx.x * blockDim.x + threadIdx.x;     // 0..524287 (float4s)
    float4 v = ((const float4*)in)[idx];
    ushort4 o;
    o.x = f2bf(v.x); o.y = f2bf(v.y); o.z = f2bf(v.z); o.w = f2bf(v.w);
    ((ushort4*)Xb)[idx] = o;
    if (idx < MEM) {                                     // sentinel row NN = zeros
        cbuf[(size_t)NN * MEM + idx] = 0.0f;
        hb[(size_t)NN * MEM + idx] = 0;
    }
}

// ---------------- prep: weights -> bf16 transposed (dst[n][k] = src[k][n]) ---
__global__ void prep_w(const float* __restrict__ Wx, const float* __restrict__ Ws,
                       const float* __restrict__ Wf, unsigned short* __restrict__ WxT,
                       unsigned short* __restrict__ WsT, unsigned short* __restrict__ WfT) {
    int t = blockIdx.x * blockDim.x + threadIdx.x;       // 524288 threads, 4 elems each
    int base = t * 4;
    const float* src; unsigned short* dst; int ncols, n, k;
    if (base < 2048 * 512)              { src = Wx; dst = WxT; ncols = 2048; n = base >> 9; k = base & 511; }
    else if (base < (2048 + 1536) * 512){ int b = base - 2048 * 512;
                                          src = Ws; dst = WsT; ncols = 1536; n = b >> 9; k = b & 511; }
    else                                { int b = base - (2048 + 1536) * 512;
                                          src = Wf; dst = WfT; ncols = 512;  n = b >> 9; k = b & 511; }
    ushort4 o;
    o.x = f2bf(src[(size_t)(k + 0) * ncols + n]);
    o.y = f2bf(src[(size_t)(k + 1) * ncols + n]);
    o.z = f2bf(src[(size_t)(k + 2) * ncols + n]);
    o.w = f2bf(src[(size_t)(k + 3) * ncols + n]);
    *(ushort4*)(dst + (size_t)n * KD + k) = o;
}

// ---------------- bf16 MFMA GEMM, 128x128 tile, BK=64, 256 threads ----------
// C[M,Nn] = Arows @ Bt^T + bias, K = 512 fixed.
// MODE 0: A row r = Abase[r]                       (Abase = bf16 [M][512])
// MODE 1: A row r = sum_k hb[children[lo+r][k]]    (Abase = hb)
// MODE 2: A row r = hb[children[lo + r/4][r%4]]    (Abase = hb)
template <int MODE>
__global__ __launch_bounds__(256) void gemm_bf16(
    const unsigned short* __restrict__ Abase,
    const unsigned short* __restrict__ Bt,   // [Nn][512] bf16 (k-contiguous)
    const float* __restrict__ bias,          // [Nn]
    float* __restrict__ C,                   // [M][Nn] fp32
    const int* __restrict__ children, int lo,
    int M, int Nn) {
    __shared__ __align__(16) char As[128 * 64 * 2];
    __shared__ __align__(16) char Bs[128 * 64 * 2];

    const int bn = blockIdx.x * 128;
    const int bm = blockIdx.y * 128;
    const int tid = threadIdx.x;
    const int wave = tid >> 6;
    const int lane = tid & 63;
    const int wm = (wave >> 1) * 64;
    const int wn = (wave & 1) * 64;

    f32x4 acc[4][4];
#pragma unroll
    for (int a = 0; a < 4; ++a)
#pragma unroll
        for (int b = 0; b < 4; ++b) acc[a][b] = (f32x4){0.f, 0.f, 0.f, 0.f};

    // staging chunk map: chunk c (0..1023): row = c>>3, kc = (c&7)*8 elements
    int rowA[4], kcA[4];
    int kid[4][4];
#pragma unroll
    for (int i = 0; i < 4; ++i) {
        int c = tid + i * 256;
        rowA[i] = c >> 3;
        kcA[i] = (c & 7) * 8;
        if (MODE == 1) {
            int node = bm + rowA[i];
            if (node < M) {
                const int* kk = children + (size_t)(lo + node) * 4;
                kid[i][0] = kk[0]; kid[i][1] = kk[1]; kid[i][2] = kk[2]; kid[i][3] = kk[3];
            } else {
                kid[i][0] = kid[i][1] = kid[i][2] = kid[i][3] = NN;  // zero row
            }
        } else if (MODE == 2) {
            int frow = bm + rowA[i];
            kid[i][0] = (frow < M) ? children[(size_t)(lo + (frow >> 2)) * 4 + (frow & 3)] : NN;
        }
    }

    for (int k0 = 0; k0 < KD; k0 += 64) {
        bf16x8 ar[4], br[4];
#pragma unroll
        for (int i = 0; i < 4; ++i) {
            const int row = rowA[i], kc = kcA[i];
            if (MODE == 0) {
                int grow = bm + row;
                ar[i] = (grow < M) ? *(const bf16x8*)(Abase + (size_t)grow * KD + k0 + kc)
                                   : zero8();
            } else if (MODE == 1) {
                bf16x8 h0 = *(const bf16x8*)(Abase + (size_t)kid[i][0] * KD + k0 + kc);
                bf16x8 h1 = *(const bf16x8*)(Abase + (size_t)kid[i][1] * KD + k0 + kc);
                bf16x8 h2 = *(const bf16x8*)(Abase + (size_t)kid[i][2] * KD + k0 + kc);
                bf16x8 h3 = *(const bf16x8*)(Abase + (size_t)kid[i][3] * KD + k0 + kc);
                bf16x8 s;
#pragma unroll
                for (int j = 0; j < 8; ++j) {
                    float f = bf2f((unsigned short)h0[j]) + bf2f((unsigned short)h1[j]) +
                              bf2f((unsigned short)h2[j]) + bf2f((unsigned short)h3[j]);
                    s[j] = (short)f2bf(f);
                }
                ar[i] = s;
            } else {
                ar[i] = *(const bf16x8*)(Abase + (size_t)kid[i][0] * KD + k0 + kc);
            }
            br[i] = *(const bf16x8*)(Bt + (size_t)(bn + row) * KD + k0 + kc);
        }
        __syncthreads();
#pragma unroll
        for (int i = 0; i < 4; ++i) {
            const int row = rowA[i], kc = kcA[i];
            const int off = (row * 128 + kc * 2) ^ ((row & 7) << 4);
            *(bf16x8*)(As + off) = ar[i];
            *(bf16x8*)(Bs + off) = br[i];
        }
        __syncthreads();

#pragma unroll
        for (int ks = 0; ks < 2; ++ks) {
            const int kbyte = (ks * 32 + (lane >> 4) * 8) * 2;
            bf16x8 af[4], bfr[4];
#pragma unroll
            for (int mi = 0; mi < 4; ++mi) {
                int r = wm + mi * 16 + (lane & 15);
                af[mi] = *(const bf16x8*)(As + ((r * 128 + kbyte) ^ ((r & 7) << 4)));
            }
#pragma unroll
            for (int ni = 0; ni < 4; ++ni) {
                int r = wn + ni * 16 + (lane & 15);
                bfr[ni] = *(const bf16x8*)(Bs + ((r * 128 + kbyte) ^ ((r & 7) << 4)));
            }
#pragma unroll
            for (int mi = 0; mi < 4; ++mi)
#pragma unroll
                for (int ni = 0; ni < 4; ++ni)
                    acc[mi][ni] = __builtin_amdgcn_mfma_f32_16x16x32_bf16(
                        af[mi], bfr[ni], acc[mi][ni], 0, 0, 0);
        }
    }

    // epilogue: D lane mapping col = lane&15, row = (lane>>4)*4 + j
#pragma unroll
    for (int mi = 0; mi < 4; ++mi) {
#pragma unroll
        for (int j = 0; j < 4; ++j) {
            int r = bm + wm + mi * 16 + (lane >> 4) * 4 + j;
            if (r < M) {
#pragma unroll
                for (int ni = 0; ni < 4; ++ni) {
                    int cl = bn + wn + ni * 16 + (lane & 15);
                    C[(size_t)r * Nn + cl] = acc[mi][ni][j] + bias[cl];
                }
            }
        }
    }
}

// ---------------- leaves: elementwise from XW + bs ---------------------------
__global__ void leaf_update(const float* __restrict__ XW, const float* __restrict__ bsv,
                            float* __restrict__ cbuf, unsigned short* __restrict__ hb) {
    const int n = blockIdx.x;
    const int d = threadIdx.x;
    const float* xwr = XW + (size_t)n * (4 * MEM);
    const float ig = sigmoidf_(xwr[d] + bsv[d]);
    const float og = sigmoidf_(xwr[2 * MEM + d] + bsv[MEM + d]);
    const float ug = tanhf(xwr[3 * MEM + d] + bsv[2 * MEM + d]);
    const float c = ig * ug;
    cbuf[(size_t)n * MEM + d] = c;
    hb[(size_t)n * MEM + d] = f2bf(og * tanhf(c));
}

// ---------------- internal node update ---------------------------------------
__global__ void node_update(const float* __restrict__ XW, const float* __restrict__ IOU,
                            const float* __restrict__ Fpre, const int* __restrict__ children,
                            float* __restrict__ cbuf, unsigned short* __restrict__ hb,
                            float* __restrict__ outp, int lo) {
    const int i = blockIdx.x;
    const int n = lo + i;
    const int d = threadIdx.x;
    const float* xwr = XW + (size_t)n * (4 * MEM);
    const float ix = xwr[d];
    const float fx = xwr[MEM + d];
    const float ox = xwr[2 * MEM + d];
    const float ux = xwr[3 * MEM + d];
    const float* r = IOU + (size_t)i * (3 * MEM);
    const float ig = sigmoidf_(ix + r[d]);
    const float og = sigmoidf_(ox + r[MEM + d]);
    const float ug = tanhf(ux + r[2 * MEM + d]);
    float c = ig * ug;
    const int* kk = children + (size_t)n * 4;
#pragma unroll
    for (int k = 0; k < 4; ++k) {
        const float f = sigmoidf_(Fpre[((size_t)i * 4 + k) * MEM + d] + fx);
        c += f * cbuf[(size_t)kk[k] * MEM + d];
    }
    cbuf[(size_t)n * MEM + d] = c;
    const float h = og * tanhf(c);
    hb[(size_t)n * MEM + d] = f2bf(h);
    if (outp) outp[d] = h;
}

extern "C" void kernel_launch(void* const* d_in, const int* in_sizes, int n_in,
                              void* d_out, int out_size, void* d_ws, size_t ws_size,
                              hipStream_t stream) {
    const float* inputs   = (const float*)d_in[0];
    const float* Wx       = (const float*)d_in[1];
    const float* bx       = (const float*)d_in[2];
    const float* Ws       = (const float*)d_in[3];
    const float* bs       = (const float*)d_in[4];
    const float* Wf       = (const float*)d_in[5];
    const float* bfv      = (const float*)d_in[6];
    const int*   children = (const int*)d_in[7];
    float* out = (float*)d_out;

    // workspace layout
    float* XW   = (float*)d_ws;                                  // 4096*2048 f32
    float* cbuf = XW + (size_t)NN * 4 * MEM;                     // 4097*512 f32
    float* IOU  = cbuf + (size_t)(NN + 1) * MEM;                 // 683*1536 f32
    float* Fpre = IOU + (size_t)683 * 1536;                      // 2732*512 f32
    unsigned short* hb  = (unsigned short*)(Fpre + (size_t)2732 * 512);  // 4097*512 bf16
    unsigned short* Xb  = hb + (size_t)(NN + 1) * MEM;           // 4096*512 bf16
    unsigned short* WxT = Xb + (size_t)NN * MEM;                 // 2048*512 bf16
    unsigned short* WsT = WxT + (size_t)2048 * 512;              // 1536*512 bf16
    unsigned short* WfT = WsT + (size_t)1536 * 512;              // 512*512 bf16

    prep_x<<<2048, 256, 0, stream>>>(inputs, Xb, cbuf, hb);
    prep_w<<<2048, 256, 0, stream>>>(Wx, Ws, Wf, WxT, WsT, WfT);

    // XW = inputs @ Wx + bx
    gemm_bf16<0><<<dim3(2048 / 128, 4096 / 128), 256, 0, stream>>>(
        Xb, WxT, bx, XW, nullptr, 0, NN, 2048);

    // leaves [0, 3072)
    leaf_update<<<3072, 512, 0, stream>>>(XW, bs, cbuf, hb);

    static const int lvl_lo[6] = {3072, 3755, 4011, 4075, 4091, 4095};
    static const int lvl_L[6]  = {683, 256, 64, 16, 4, 1};

    for (int l = 0; l < 6; ++l) {
        const int lo = lvl_lo[l];
        const int L  = lvl_L[l];

        // IOU[L,1536] = hsum @ Ws + bs   (gather fused into A staging)
        gemm_bf16<1><<<dim3(1536 / 128, (L + 127) / 128), 256, 0, stream>>>(
            hb, WsT, bs, IOU, children, lo, L, 1536);

        // Fpre[4L,512] = child_h @ Wf + bf
        gemm_bf16<2><<<dim3(512 / 128, (4 * L + 127) / 128), 256, 0, stream>>>(
            hb, WfT, bfv, Fpre, children, lo, 4 * L, 512);

        node_update<<<L, 512, 0, stream>>>(
            XW, IOU, Fpre, children, cbuf, hb, (l == 5) ? out : nullptr, lo);
    }
}